// Round 1
// baseline (11035.937 us; speedup 1.0000x reference)
//
#include <hip/hip_runtime.h>
#include <hip/hip_bf16.h>
#include <hip/hip_cooperative_groups.h>

namespace cg = cooperative_groups;

// Problem dims
#define Bb 256
#define Tt 256
#define Dd 512
#define Hh 1024
#define Cc 1000

typedef short  bf16x4 __attribute__((ext_vector_type(4)));
typedef float  f32x4  __attribute__((ext_vector_type(4)));
typedef unsigned short u16x4 __attribute__((ext_vector_type(4)));

// K-chunking: 16 k per chunk (MFMA 16x16x16)
#define XCH 32              // x chunks (D=512)
#define HCH 64              // h chunks (H=1024)
#define CI_Z  0             // z: 32 x-chunks then 64 h-chunks
#define CI_R  96            // r: same
#define CI_XH 192           // xh: 32 x-chunks
#define CI_HU 224           // hU: 64 h-chunks
#define NCI   288           // total chunks per 16-col block
// packed weights: [cblk(64)][ci(288)][lane(64)][4 elems] bf16 = 9,437,184 B

__device__ __forceinline__ unsigned short f2bf(float f) {
  unsigned u = __float_as_uint(f);
  u += 0x7FFFu + ((u >> 16) & 1u);       // RNE
  return (unsigned short)(u >> 16);
}

// ---------------- pack weights into MFMA-fragment order (bf16) ----------------
__global__ void pack_weights(const float* __restrict__ Wz, const float* __restrict__ Wr,
                             const float* __restrict__ W,  const float* __restrict__ Uz,
                             const float* __restrict__ Ur, const float* __restrict__ U,
                             unsigned short* __restrict__ packed) {
  int tid = blockIdx.x * 256 + threadIdx.x;           // one thread = one (c,ci,lane) -> 4 elems
  if (tid >= 64 * NCI * 64) return;
  int lane = tid & 63;
  int rest = tid >> 6;
  int ci   = rest % NCI;
  int c    = rest / NCI;                               // 0..63 col block
  int j    = (c << 4) + (lane & 15);                   // output column
  int kg   = lane >> 4;                                // 0..3
  const float* src; int kb;
  if (ci < CI_R)       { int q = ci;         if (q < XCH) { src = Wz; kb = q*16; } else { src = Uz; kb = (q-XCH)*16; } }
  else if (ci < CI_XH) { int q = ci - CI_R;  if (q < XCH) { src = Wr; kb = q*16; } else { src = Ur; kb = (q-XCH)*16; } }
  else if (ci < CI_HU) { int q = ci - CI_XH; src = W; kb = q*16; }
  else                 { int q = ci - CI_HU; src = U; kb = q*16; }
  int k0 = kb + kg*4;
  u16x4 o;
  #pragma unroll
  for (int e = 0; e < 4; ++e) o[e] = f2bf(src[(size_t)(k0+e)*Hh + j]);
  *(u16x4*)(packed + (size_t)tid*4) = o;
}

// ---------------- x fp32 -> bf16 (optional, if ws is big enough) ----------------
__global__ void cvt_x(const float* __restrict__ x, unsigned short* __restrict__ xb) {
  const int n4 = (Bb*Tt*Dd)/4;
  for (int i = blockIdx.x*256 + threadIdx.x; i < n4; i += gridDim.x*256) {
    f32x4 v = *(const f32x4*)(x + (size_t)i*4);
    u16x4 o;
    #pragma unroll
    for (int e = 0; e < 4; ++e) o[e] = f2bf(v[e]);
    *(u16x4*)(xb + (size_t)i*4) = o;
  }
}

// ---------------- persistent cooperative GRU scan ----------------
// grid = 256 WGs (4 row-blocks x 64 col-blocks), 256 threads (4 waves x 16 rows)
template<bool XBF>
__global__ void __launch_bounds__(256, 1)
gru_scan(const float* __restrict__ x, const unsigned short* __restrict__ xb,
         const unsigned short* __restrict__ packed,
         float* __restrict__ hf, unsigned short* __restrict__ hb) {
  cg::grid_group grid = cg::this_grid();
  __shared__ unsigned short lds[NCI * 256];            // 147,456 B: this col-block's weights

  const int wg   = blockIdx.x;
  const int cblk = wg & 63;
  const int rblk = wg >> 6;
  const int tid  = threadIdx.x;
  const int lane = tid & 63;
  const int wave = tid >> 6;

  { // stage weights into LDS once (coalesced 8B copies)
    const u16x4* s4 = (const u16x4*)(packed + (size_t)cblk * (NCI * 256));
    u16x4* d4 = (u16x4*)lds;
    for (int i = tid; i < NCI * 64; i += 256) d4[i] = s4[i];
  }
  __syncthreads();

  const int arow = lane & 15;                  // A row within wave's 16-row tile
  const int kg   = lane >> 4;                  // k-group 0..3
  const int b    = rblk*64 + wave*16 + arow;   // A-operand batch row
  const int crow = rblk*64 + wave*16 + kg*4;   // C/D row base (+e)
  const int j    = (cblk << 4) + arow;         // C/D column (lane&15)

  const float*          xrow  = x  + (size_t)b * Tt * Dd;
  const unsigned short* xbrow = xb + (size_t)b * Tt * Dd;

  for (int t = 0; t < Tt; ++t) {
    const int rd = t & 1, wr = rd ^ 1;
    const unsigned short* hrow = hb + rd*(Bb*Hh) + b*Hh;

    f32x4 az  = {0.f,0.f,0.f,0.f};
    f32x4 ar  = {0.f,0.f,0.f,0.f};
    f32x4 axh = {0.f,0.f,0.f,0.f};
    f32x4 ahu = {0.f,0.f,0.f,0.f};

    if constexpr (XBF) {
      const unsigned short* xt = xbrow + t*Dd;
      #pragma unroll 8
      for (int kk = 0; kk < XCH; ++kk) {
        bf16x4 a  = *(const bf16x4*)(xt + kk*16 + kg*4);
        bf16x4 bz = *(const bf16x4*)&lds[(CI_Z  + kk)*256 + lane*4];
        bf16x4 br = *(const bf16x4*)&lds[(CI_R  + kk)*256 + lane*4];
        bf16x4 bx = *(const bf16x4*)&lds[(CI_XH + kk)*256 + lane*4];
        az  = __builtin_amdgcn_mfma_f32_16x16x16bf16_1k(a, bz, az , 0,0,0);
        ar  = __builtin_amdgcn_mfma_f32_16x16x16bf16_1k(a, br, ar , 0,0,0);
        axh = __builtin_amdgcn_mfma_f32_16x16x16bf16_1k(a, bx, axh, 0,0,0);
      }
    } else {
      const float* xt = xrow + t*Dd;
      #pragma unroll 8
      for (int kk = 0; kk < XCH; ++kk) {
        f32x4 v = *(const f32x4*)(xt + kk*16 + kg*4);
        bf16x4 a;
        #pragma unroll
        for (int e = 0; e < 4; ++e) ((unsigned short*)&a)[e] = f2bf(v[e]);
        bf16x4 bz = *(const bf16x4*)&lds[(CI_Z  + kk)*256 + lane*4];
        bf16x4 br = *(const bf16x4*)&lds[(CI_R  + kk)*256 + lane*4];
        bf16x4 bx = *(const bf16x4*)&lds[(CI_XH + kk)*256 + lane*4];
        az  = __builtin_amdgcn_mfma_f32_16x16x16bf16_1k(a, bz, az , 0,0,0);
        ar  = __builtin_amdgcn_mfma_f32_16x16x16bf16_1k(a, br, ar , 0,0,0);
        axh = __builtin_amdgcn_mfma_f32_16x16x16bf16_1k(a, bx, axh, 0,0,0);
      }
    }

    #pragma unroll 8
    for (int kk = 0; kk < HCH; ++kk) {
      bf16x4 a  = *(const bf16x4*)(hrow + kk*16 + kg*4);
      bf16x4 bz = *(const bf16x4*)&lds[(CI_Z + XCH + kk)*256 + lane*4];
      bf16x4 br = *(const bf16x4*)&lds[(CI_R + XCH + kk)*256 + lane*4];
      bf16x4 bu = *(const bf16x4*)&lds[(CI_HU      + kk)*256 + lane*4];
      az  = __builtin_amdgcn_mfma_f32_16x16x16bf16_1k(a, bz, az , 0,0,0);
      ar  = __builtin_amdgcn_mfma_f32_16x16x16bf16_1k(a, br, ar , 0,0,0);
      ahu = __builtin_amdgcn_mfma_f32_16x16x16bf16_1k(a, bu, ahu, 0,0,0);
    }

    // gate epilogue: h_new = z*h + (1-z)*tanh(xh + (hU)*r)
    const float* hfr = hf + rd*(Bb*Hh);
    float*       hfw = hf + wr*(Bb*Hh);
    unsigned short* hbw = hb + wr*(Bb*Hh);
    #pragma unroll
    for (int e = 0; e < 4; ++e) {
      int   bi   = crow + e;
      float z    = 1.f / (1.f + __expf(-az[e]));
      float r    = 1.f / (1.f + __expf(-ar[e]));
      float u    = axh[e] + ahu[e] * r;
      float hh   = 2.f / (1.f + __expf(-2.f * u)) - 1.f;    // tanh
      float hold = hfr[bi*Hh + j];
      float hn   = z*hold + (1.f - z)*hh;
      hfw[bi*Hh + j] = hn;
      hbw[bi*Hh + j] = f2bf(hn);
    }
    grid.sync();
  }
}

// ---------------- classifier: p = h_last @ W_ph + b_p ----------------
__global__ void classifier(const float* __restrict__ h, const float* __restrict__ Wph,
                           const float* __restrict__ bp, float* __restrict__ out) {
  __shared__ float hsm[8 * Hh];                 // transposed: [k][r]
  const int cb = blockIdx.x, bbk = blockIdx.y;
  const int tid = threadIdx.x;
  const float* h0 = h + (size_t)bbk * 8 * Hh;
  for (int i = tid; i < 8 * Hh; i += 256) {
    int r = i >> 10, k = i & (Hh - 1);
    hsm[k*8 + r] = h0[i];
  }
  __syncthreads();
  int c = cb*256 + tid;
  bool act = c < Cc;
  float acc[8] = {0,0,0,0,0,0,0,0};
  for (int k = 0; k < Hh; ++k) {
    float w = act ? Wph[(size_t)k*Cc + c] : 0.f;
    f32x4 h0v = *(const f32x4*)&hsm[k*8];
    f32x4 h1v = *(const f32x4*)&hsm[k*8 + 4];
    acc[0] += h0v[0]*w; acc[1] += h0v[1]*w; acc[2] += h0v[2]*w; acc[3] += h0v[3]*w;
    acc[4] += h1v[0]*w; acc[5] += h1v[1]*w; acc[6] += h1v[2]*w; acc[7] += h1v[3]*w;
  }
  if (act) {
    float bias = bp[c];
    #pragma unroll
    for (int r = 0; r < 8; ++r) out[(size_t)(bbk*8 + r)*Cc + c] = acc[r] + bias;
  }
}

// ---------------- in-place log_softmax over rows of [256,1000] ----------------
__global__ void logsoftmax(float* __restrict__ out) {
  __shared__ float sm[4];
  float* row = out + (size_t)blockIdx.x * Cc;
  const int tid = threadIdx.x;
  float m = -3.4e38f;
  for (int i = tid; i < Cc; i += 256) m = fmaxf(m, row[i]);
  #pragma unroll
  for (int o = 32; o; o >>= 1) m = fmaxf(m, __shfl_down(m, o, 64));
  if ((tid & 63) == 0) sm[tid >> 6] = m;
  __syncthreads();
  m = fmaxf(fmaxf(sm[0], sm[1]), fmaxf(sm[2], sm[3]));
  __syncthreads();
  float s = 0.f;
  for (int i = tid; i < Cc; i += 256) s += __expf(row[i] - m);
  #pragma unroll
  for (int o = 32; o; o >>= 1) s += __shfl_down(s, o, 64);
  if ((tid & 63) == 0) sm[tid >> 6] = s;
  __syncthreads();
  s = sm[0] + sm[1] + sm[2] + sm[3];
  float lse = m + __logf(s);
  for (int i = tid; i < Cc; i += 256) row[i] -= lse;
}

extern "C" void kernel_launch(void* const* d_in, const int* in_sizes, int n_in,
                              void* d_out, int out_size, void* d_ws, size_t ws_size,
                              hipStream_t stream) {
  (void)in_sizes; (void)n_in; (void)out_size;
  const float* x   = (const float*)d_in[0];
  const float* Wz  = (const float*)d_in[1];
  const float* Wr  = (const float*)d_in[2];
  const float* W   = (const float*)d_in[3];
  const float* Uz  = (const float*)d_in[4];
  const float* Ur  = (const float*)d_in[5];
  const float* U   = (const float*)d_in[6];
  const float* Wph = (const float*)d_in[7];
  const float* bp  = (const float*)d_in[8];
  float* out = (float*)d_out;

  char* ws = (char*)d_ws;
  const size_t OFF_PACK = 0;                       // 9,437,184 B
  const size_t OFF_HF   = 9437184;                 // 2,097,152 B (2 x [256,1024] fp32)
  const size_t OFF_HB   = OFF_HF + 2097152;        // 1,048,576 B (2 x [256,1024] bf16)
  const size_t OFF_XB   = OFF_HB + 1048576;        // 67,108,864 B ([B,T,D] bf16)
  unsigned short* packed = (unsigned short*)(ws + OFF_PACK);
  float*          hf     = (float*)(ws + OFF_HF);
  unsigned short* hb     = (unsigned short*)(ws + OFF_HB);
  unsigned short* xbm    = (unsigned short*)(ws + OFF_XB);
  const bool xbf = ws_size >= OFF_XB + (size_t)67108864;

  // zero h state (both fp32 and bf16 double-buffers) every call
  hipMemsetAsync(hf, 0, 2097152 + 1048576, stream);
  pack_weights<<<dim3(4608), dim3(256), 0, stream>>>(Wz, Wr, W, Uz, Ur, U, packed);
  if (xbf) cvt_x<<<dim3(2048), dim3(256), 0, stream>>>(x, xbm);

  void* args[] = { (void*)&x, (void*)&xbm, (void*)&packed, (void*)&hf, (void*)&hb };
  if (xbf) {
    hipLaunchCooperativeKernel(reinterpret_cast<void*>(&gru_scan<true>),
                               dim3(256), dim3(256), args, 0, stream);
  } else {
    hipLaunchCooperativeKernel(reinterpret_cast<void*>(&gru_scan<false>),
                               dim3(256), dim3(256), args, 0, stream);
  }

  classifier<<<dim3(4, 32), dim3(256), 0, stream>>>(hf /*buf0 = h_last*/, Wph, bp, out);
  logsoftmax<<<dim3(256), dim3(256), 0, stream>>>(out);
}

// Round 2
// 6740.711 us; speedup vs baseline: 1.6372x; 1.6372x over previous
//
#include <hip/hip_runtime.h>
#include <hip/hip_bf16.h>

// Problem dims
#define Bb 256
#define Tt 256
#define Dd 512
#define Hh 1024
#define Cc 1000

typedef short  bf16x8 __attribute__((ext_vector_type(8)));
typedef float  f32x4  __attribute__((ext_vector_type(4)));
typedef unsigned short u16x8 __attribute__((ext_vector_type(8)));

// 32-k chunks for MFMA 16x16x32. Per 16-col block:
//  z : 16 x-chunks [0,16) + 32 h-chunks [16,48)
//  r : 16 x-chunks [48,64) + 32 h-chunks [64,96)
//  xh: 16 x-chunks [96,112)
//  hU: 32 h-chunks [112,144)
#define NCI 144
// packed: [cblk(64)][ci(144)][lane(64)][8 elems] bf16 = 9,437,184 B

__device__ __forceinline__ unsigned short f2bf(float f) {
  unsigned u = __float_as_uint(f);
  u += 0x7FFFu + ((u >> 16) & 1u);       // RNE
  return (unsigned short)(u >> 16);
}

// ---------------- pack weights into MFMA-fragment order (bf16) ----------------
// B-fragment for 16x16x32: col = lane&15, k = (lane>>4)*8 + e
__global__ void pack_weights(const float* __restrict__ Wz, const float* __restrict__ Wr,
                             const float* __restrict__ W,  const float* __restrict__ Uz,
                             const float* __restrict__ Ur, const float* __restrict__ U,
                             unsigned short* __restrict__ packed) {
  int tid = blockIdx.x * 256 + threadIdx.x;           // one thread = one (c,ci,lane) -> 8 elems
  if (tid >= 64 * NCI * 64) return;
  int lane = tid & 63;
  int rest = tid >> 6;
  int ci   = rest % NCI;
  int c    = rest / NCI;                               // 0..63 col block
  int j    = (c << 4) + (lane & 15);                   // output column
  int kg   = lane >> 4;                                // 0..3
  const float* src; int kb;
  if      (ci < 16)  { src = Wz; kb = ci*32; }
  else if (ci < 48)  { src = Uz; kb = (ci-16)*32; }
  else if (ci < 64)  { src = Wr; kb = (ci-48)*32; }
  else if (ci < 96)  { src = Ur; kb = (ci-64)*32; }
  else if (ci < 112) { src = W;  kb = (ci-96)*32; }
  else               { src = U;  kb = (ci-112)*32; }
  int k0 = kb + kg*8;
  u16x8 o;
  #pragma unroll
  for (int e = 0; e < 8; ++e) o[e] = f2bf(src[(size_t)(k0+e)*Hh + j]);
  *(u16x8*)(packed + (size_t)tid*8) = o;
}

// ---------------- x fp32 -> bf16 (optional, if ws is big enough) ----------------
__global__ void cvt_x(const float* __restrict__ x, unsigned short* __restrict__ xb) {
  const int n4 = (Bb*Tt*Dd)/4;
  for (int i = blockIdx.x*256 + threadIdx.x; i < n4; i += gridDim.x*256) {
    f32x4 v = *(const f32x4*)(x + (size_t)i*4);
    unsigned short o[4];
    #pragma unroll
    for (int e = 0; e < 4; ++e) o[e] = f2bf(v[e]);
    *(unsigned long long*)(xb + (size_t)i*4) = *(unsigned long long*)o;
  }
}

// ---------------- persistent GRU scan, custom per-row-block barriers ----------------
// grid = 256 WGs (4 row-blocks x 64 col-blocks), 256 threads (4 waves x 16 rows)
// barrier state in ws: done[4][64] u32 at bar[0..255]; flag[g] at bar[256 + g*16]
template<bool XBF>
__global__ void __launch_bounds__(256, 1)
gru_scan(const float* __restrict__ x, const unsigned short* __restrict__ xb,
         const unsigned short* __restrict__ packed,
         float* __restrict__ hf, unsigned short* __restrict__ hb,
         unsigned* __restrict__ bar) {
  __shared__ short lds[NCI * 512];                     // 147,456 B weight slice

  const int wg   = blockIdx.x;
  const int cblk = wg & 63;
  const int rblk = wg >> 6;
  const int tid  = threadIdx.x;
  const int lane = tid & 63;
  const int wave = tid >> 6;

  { // stage weights into LDS once (16B copies)
    const u16x8* s8 = (const u16x8*)(packed + (size_t)cblk * (NCI * 512));
    u16x8* d8 = (u16x8*)lds;
    for (int i = tid; i < NCI * 64; i += 256) d8[i] = s8[i];
  }
  __syncthreads();

  const int arow = lane & 15;                  // A row within wave's 16-row tile
  const int kg   = lane >> 4;                  // k-group 0..3 (k = kg*8 + e)
  const int b    = rblk*64 + wave*16 + arow;   // A-operand batch row
  const int crow = rblk*64 + wave*16 + kg*4;   // C/D row base (+e)
  const int j    = (cblk << 4) + arow;         // C/D column

  unsigned* done = bar + rblk*64;              // this group's 64 arrival slots
  unsigned* flag = bar + 256 + rblk*16;        // this group's release flag

  const float*          xrow  = x  + (size_t)b * Tt * Dd;
  const unsigned short* xbrow = xb + (size_t)b * Tt * Dd;

  f32x4 hold = {0.f,0.f,0.f,0.f};              // fp32 h master, register-resident

  // prefetch x_0 fragments
  bf16x8 xa[16];
  if constexpr (XBF) {
    #pragma unroll
    for (int kk = 0; kk < 16; ++kk) xa[kk] = *(const bf16x8*)(xbrow + kk*32 + kg*8);
  } else {
    #pragma unroll
    for (int kk = 0; kk < 16; ++kk) {
      f32x4 v0 = *(const f32x4*)(xrow + kk*32 + kg*8);
      f32x4 v1 = *(const f32x4*)(xrow + kk*32 + kg*8 + 4);
      bf16x8 a;
      #pragma unroll
      for (int e = 0; e < 4; ++e) { ((unsigned short*)&a)[e] = f2bf(v0[e]); ((unsigned short*)&a)[e+4] = f2bf(v1[e]); }
      xa[kk] = a;
    }
  }

  for (int t = 0; t < Tt; ++t) {
    const int rd = t & 1, wr = rd ^ 1;
    const unsigned short* hrow = hb + rd*(Bb*Hh) + b*Hh;

    // issue all h-fragment loads first (L2-resident, pipeline under x MFMAs)
    bf16x8 ha[32];
    #pragma unroll
    for (int kk = 0; kk < 32; ++kk) ha[kk] = *(const bf16x8*)(hrow + kk*32 + kg*8);

    f32x4 az  = {0.f,0.f,0.f,0.f};
    f32x4 arr = {0.f,0.f,0.f,0.f};
    f32x4 axh = {0.f,0.f,0.f,0.f};
    f32x4 ahu = {0.f,0.f,0.f,0.f};

    // x-part (operands already in registers)
    #pragma unroll
    for (int kk = 0; kk < 16; ++kk) {
      bf16x8 bz = *(const bf16x8*)&lds[(0  + kk)*512 + lane*8];
      bf16x8 br = *(const bf16x8*)&lds[(48 + kk)*512 + lane*8];
      bf16x8 bx = *(const bf16x8*)&lds[(96 + kk)*512 + lane*8];
      az  = __builtin_amdgcn_mfma_f32_16x16x32_bf16(xa[kk], bz, az , 0,0,0);
      arr = __builtin_amdgcn_mfma_f32_16x16x32_bf16(xa[kk], br, arr, 0,0,0);
      axh = __builtin_amdgcn_mfma_f32_16x16x32_bf16(xa[kk], bx, axh, 0,0,0);
    }
    // h-part
    #pragma unroll
    for (int kk = 0; kk < 32; ++kk) {
      bf16x8 bz = *(const bf16x8*)&lds[(16  + kk)*512 + lane*8];
      bf16x8 br = *(const bf16x8*)&lds[(64  + kk)*512 + lane*8];
      bf16x8 bu = *(const bf16x8*)&lds[(112 + kk)*512 + lane*8];
      az  = __builtin_amdgcn_mfma_f32_16x16x32_bf16(ha[kk], bz, az , 0,0,0);
      arr = __builtin_amdgcn_mfma_f32_16x16x32_bf16(ha[kk], br, arr, 0,0,0);
      ahu = __builtin_amdgcn_mfma_f32_16x16x32_bf16(ha[kk], bu, ahu, 0,0,0);
    }

    // prefetch x_{t+1} fragments (independent of the barrier)
    if (t + 1 < Tt) {
      if constexpr (XBF) {
        const unsigned short* xt = xbrow + (t+1)*Dd;
        #pragma unroll
        for (int kk = 0; kk < 16; ++kk) xa[kk] = *(const bf16x8*)(xt + kk*32 + kg*8);
      } else {
        const float* xt = xrow + (t+1)*Dd;
        #pragma unroll
        for (int kk = 0; kk < 16; ++kk) {
          f32x4 v0 = *(const f32x4*)(xt + kk*32 + kg*8);
          f32x4 v1 = *(const f32x4*)(xt + kk*32 + kg*8 + 4);
          bf16x8 a;
          #pragma unroll
          for (int e = 0; e < 4; ++e) { ((unsigned short*)&a)[e] = f2bf(v0[e]); ((unsigned short*)&a)[e+4] = f2bf(v1[e]); }
          xa[kk] = a;
        }
      }
    }

    // gate epilogue: h_new = z*h + (1-z)*tanh(xh + (hU)*r)
    unsigned short* hbw = hb + wr*(Bb*Hh);
    #pragma unroll
    for (int e = 0; e < 4; ++e) {
      float z  = 1.f / (1.f + __expf(-az[e]));
      float r  = 1.f / (1.f + __expf(-arr[e]));
      float u  = axh[e] + ahu[e] * r;
      float hh = 2.f / (1.f + __expf(-2.f * u)) - 1.f;    // tanh
      float hn = z*hold[e] + (1.f - z)*hh;
      hold[e]  = hn;
      hbw[(size_t)(crow+e)*Hh + j] = f2bf(hn);
    }
    if (t == Tt - 1) {
      #pragma unroll
      for (int e = 0; e < 4; ++e) hf[(size_t)(crow+e)*Hh + j] = hold[e];
    }

    // ---- per-row-block barrier (64 WGs) ----
    const unsigned target = (unsigned)(t + 1);
    __syncthreads();                                      // all waves' stores issued
    if (tid == 0) {
      __hip_atomic_store(&done[cblk], target, __ATOMIC_RELEASE, __HIP_MEMORY_SCOPE_AGENT);
    }
    if (cblk == 0 && wave == 0) {                         // leader WG: 64 lanes poll 64 slots
      for (;;) {
        unsigned v = __hip_atomic_load(&done[lane], __ATOMIC_ACQUIRE, __HIP_MEMORY_SCOPE_AGENT);
        if (__all((int)(v >= target))) break;
        __builtin_amdgcn_s_sleep(1);
      }
      if (lane == 0)
        __hip_atomic_store(flag, target, __ATOMIC_RELEASE, __HIP_MEMORY_SCOPE_AGENT);
    }
    if (tid == 0) {
      while (__hip_atomic_load(flag, __ATOMIC_ACQUIRE, __HIP_MEMORY_SCOPE_AGENT) < target)
        __builtin_amdgcn_s_sleep(1);
    }
    __syncthreads();
  }
}

// ---------------- classifier: p = h_last @ W_ph + b_p ----------------
__global__ void classifier(const float* __restrict__ h, const float* __restrict__ Wph,
                           const float* __restrict__ bp, float* __restrict__ out) {
  __shared__ float hsm[8 * Hh];                 // transposed: [k][r]
  const int cb = blockIdx.x, bbk = blockIdx.y;
  const int tid = threadIdx.x;
  const float* h0 = h + (size_t)bbk * 8 * Hh;
  for (int i = tid; i < 8 * Hh; i += 256) {
    int r = i >> 10, k = i & (Hh - 1);
    hsm[k*8 + r] = h0[i];
  }
  __syncthreads();
  int c = cb*256 + tid;
  bool act = c < Cc;
  float acc[8] = {0,0,0,0,0,0,0,0};
  for (int k = 0; k < Hh; ++k) {
    float w = act ? Wph[(size_t)k*Cc + c] : 0.f;
    f32x4 h0v = *(const f32x4*)&hsm[k*8];
    f32x4 h1v = *(const f32x4*)&hsm[k*8 + 4];
    acc[0] += h0v[0]*w; acc[1] += h0v[1]*w; acc[2] += h0v[2]*w; acc[3] += h0v[3]*w;
    acc[4] += h1v[0]*w; acc[5] += h1v[1]*w; acc[6] += h1v[2]*w; acc[7] += h1v[3]*w;
  }
  if (act) {
    float bias = bp[c];
    #pragma unroll
    for (int r = 0; r < 8; ++r) out[(size_t)(bbk*8 + r)*Cc + c] = acc[r] + bias;
  }
}

// ---------------- in-place log_softmax over rows of [256,1000] ----------------
__global__ void logsoftmax(float* __restrict__ out) {
  __shared__ float sm[4];
  float* row = out + (size_t)blockIdx.x * Cc;
  const int tid = threadIdx.x;
  float m = -3.4e38f;
  for (int i = tid; i < Cc; i += 256) m = fmaxf(m, row[i]);
  #pragma unroll
  for (int o = 32; o; o >>= 1) m = fmaxf(m, __shfl_down(m, o, 64));
  if ((tid & 63) == 0) sm[tid >> 6] = m;
  __syncthreads();
  m = fmaxf(fmaxf(sm[0], sm[1]), fmaxf(sm[2], sm[3]));
  __syncthreads();
  float s = 0.f;
  for (int i = tid; i < Cc; i += 256) s += __expf(row[i] - m);
  #pragma unroll
  for (int o = 32; o; o >>= 1) s += __shfl_down(s, o, 64);
  if ((tid & 63) == 0) sm[tid >> 6] = s;
  __syncthreads();
  s = sm[0] + sm[1] + sm[2] + sm[3];
  float lse = m + __logf(s);
  for (int i = tid; i < Cc; i += 256) row[i] -= lse;
}

extern "C" void kernel_launch(void* const* d_in, const int* in_sizes, int n_in,
                              void* d_out, int out_size, void* d_ws, size_t ws_size,
                              hipStream_t stream) {
  (void)in_sizes; (void)n_in; (void)out_size;
  const float* x   = (const float*)d_in[0];
  const float* Wz  = (const float*)d_in[1];
  const float* Wr  = (const float*)d_in[2];
  const float* W   = (const float*)d_in[3];
  const float* Uz  = (const float*)d_in[4];
  const float* Ur  = (const float*)d_in[5];
  const float* U   = (const float*)d_in[6];
  const float* Wph = (const float*)d_in[7];
  const float* bp  = (const float*)d_in[8];
  float* out = (float*)d_out;

  char* ws = (char*)d_ws;
  const size_t OFF_PACK = 0;                       // 9,437,184 B
  const size_t OFF_HF   = 9437184;                 // 1,048,576 B ([256,1024] fp32, final h)
  const size_t OFF_HB   = OFF_HF + 1048576;        // 1,048,576 B (2 x [256,1024] bf16)
  const size_t OFF_BAR  = OFF_HB + 1048576;        // 4,096 B barrier state
  const size_t OFF_XB   = OFF_BAR + 4096;          // 67,108,864 B ([B,T,D] bf16)
  unsigned short* packed = (unsigned short*)(ws + OFF_PACK);
  float*          hf     = (float*)(ws + OFF_HF);
  unsigned short* hb     = (unsigned short*)(ws + OFF_HB);
  unsigned*       bar    = (unsigned*)(ws + OFF_BAR);
  unsigned short* xbm    = (unsigned short*)(ws + OFF_XB);
  const bool xbf = ws_size >= OFF_XB + (size_t)67108864;

  // zero h bf16 double-buffer + barrier state every call
  hipMemsetAsync(hb, 0, 1048576 + 4096, stream);
  pack_weights<<<dim3(2304), dim3(256), 0, stream>>>(Wz, Wr, W, Uz, Ur, U, packed);
  if (xbf) cvt_x<<<dim3(2048), dim3(256), 0, stream>>>(x, xbm);

  void* args[] = { (void*)&x, (void*)&xbm, (void*)&packed, (void*)&hf, (void*)&hb, (void*)&bar };
  if (xbf) {
    hipLaunchCooperativeKernel(reinterpret_cast<void*>(&gru_scan<true>),
                               dim3(256), dim3(256), args, 0, stream);
  } else {
    hipLaunchCooperativeKernel(reinterpret_cast<void*>(&gru_scan<false>),
                               dim3(256), dim3(256), args, 0, stream);
  }

  classifier<<<dim3(4, 32), dim3(256), 0, stream>>>(hf, Wph, bp, out);
  logsoftmax<<<dim3(256), dim3(256), 0, stream>>>(out);
}

// Round 6
// 4516.050 us; speedup vs baseline: 2.4437x; 1.4926x over previous
//
#include <hip/hip_runtime.h>
#include <hip/hip_bf16.h>

// Problem dims
#define Bb 256
#define Tt 256
#define Dd 512
#define Hh 1024
#define Cc 1000

typedef short  bf16x8 __attribute__((ext_vector_type(8)));
typedef float  f32x4  __attribute__((ext_vector_type(4)));
typedef unsigned short u16x8 __attribute__((ext_vector_type(8)));

// 32-k chunks for MFMA 16x16x32. Per 16-col block:
//  z : 16 x-chunks [0,16) + 32 h-chunks [16,48)
//  r : 16 x-chunks [48,64) + 32 h-chunks [64,96)
//  xh: 16 x-chunks [96,112)
//  hU: 32 h-chunks [112,144)
#define NCI 144
// packed: [cblk(64)][ci(144)][lane(64)][8 elems] bf16 = 9,437,184 B

__device__ __forceinline__ unsigned short f2bf(float f) {
  unsigned u = __float_as_uint(f);
  u += 0x7FFFu + ((u >> 16) & 1u);       // RNE
  return (unsigned short)(u >> 16);
}

// ---------------- pack weights into MFMA-fragment order (bf16) ----------------
// B-fragment for 16x16x32: col = lane&15, k = (lane>>4)*8 + e
__global__ void pack_weights(const float* __restrict__ Wz, const float* __restrict__ Wr,
                             const float* __restrict__ W,  const float* __restrict__ Uz,
                             const float* __restrict__ Ur, const float* __restrict__ U,
                             unsigned short* __restrict__ packed) {
  int tid = blockIdx.x * 256 + threadIdx.x;           // one thread = one (c,ci,lane) -> 8 elems
  if (tid >= 64 * NCI * 64) return;
  int lane = tid & 63;
  int rest = tid >> 6;
  int ci   = rest % NCI;
  int c    = rest / NCI;                               // 0..63 col block
  int j    = (c << 4) + (lane & 15);                   // output column
  int kg   = lane >> 4;                                // 0..3
  const float* src; int kb;
  if      (ci < 16)  { src = Wz; kb = ci*32; }
  else if (ci < 48)  { src = Uz; kb = (ci-16)*32; }
  else if (ci < 64)  { src = Wr; kb = (ci-48)*32; }
  else if (ci < 96)  { src = Ur; kb = (ci-64)*32; }
  else if (ci < 112) { src = W;  kb = (ci-96)*32; }
  else               { src = U;  kb = (ci-112)*32; }
  int k0 = kb + kg*8;
  u16x8 o;
  #pragma unroll
  for (int e = 0; e < 8; ++e) o[e] = f2bf(src[(size_t)(k0+e)*Hh + j]);
  *(u16x8*)(packed + (size_t)tid*8) = o;
}

// ---------------- x fp32 -> bf16 (optional, if ws is big enough) ----------------
__global__ void cvt_x(const float* __restrict__ x, unsigned short* __restrict__ xb) {
  const int n4 = (Bb*Tt*Dd)/4;
  for (int i = blockIdx.x*256 + threadIdx.x; i < n4; i += gridDim.x*256) {
    f32x4 v = *(const f32x4*)(x + (size_t)i*4);
    unsigned short o[4];
    #pragma unroll
    for (int e = 0; e < 4; ++e) o[e] = f2bf(v[e]);
    *(unsigned long long*)(xb + (size_t)i*4) = *(unsigned long long*)o;
  }
}

// ---------------- persistent GRU scan ----------------
// grid = 256 WGs (4 row-blocks x 64 col-blocks), 256 threads (4 waves x 16 rows).
// Coherence protocol (architected, R2-proven, cost-restructured):
//   producer: normal cached h stores -> __syncthreads (drains vmcnt) ->
//             tid0 __hip_atomic_exchange(flag, t+1, RELEASE, AGENT)  [one wbl2/step]
//   consumer: wave0 polls 64 flags with RELAXED device-scope RMW (executes at
//             coherence point, no invalidate per poll) -> ONE acquire fence
//             (buffer_inv) -> __syncthreads -> normal cached h loads.
// Flags padded to 32B to spread atomic traffic.
template<bool XBF>
__global__ void __launch_bounds__(256, 1)
gru_scan(const float* __restrict__ x, const unsigned short* __restrict__ xb,
         const unsigned short* __restrict__ packed,
         float* __restrict__ hf, unsigned short* __restrict__ hb,
         unsigned* __restrict__ bar) {
  __shared__ short lds[NCI * 512];                     // 147,456 B weight slice

  const int wg   = blockIdx.x;
  const int cblk = wg & 63;
  const int rblk = wg >> 6;
  const int tid  = threadIdx.x;
  const int lane = tid & 63;
  const int wave = tid >> 6;

  { // stage weights into LDS once (16B copies)
    const u16x8* s8 = (const u16x8*)(packed + (size_t)cblk * (NCI * 512));
    u16x8* d8 = (u16x8*)lds;
    for (int i = tid; i < NCI * 64; i += 256) d8[i] = s8[i];
  }
  __syncthreads();

  const int arow = lane & 15;                  // A row within wave's 16-row tile
  const int kg   = lane >> 4;                  // k-group 0..3 (k = kg*8 + e)
  const int b    = rblk*64 + wave*16 + arow;   // A-operand batch row
  const int crow = rblk*64 + wave*16 + kg*4;   // C/D row base (+e)
  const int j    = (cblk << 4) + arow;         // C/D column

  unsigned* const done = bar + rblk*512;       // this group's 64 flags, 8-dword stride

  const float*          xrow  = x  + (size_t)b * Tt * Dd;
  const unsigned short* xbrow = xb + (size_t)b * Tt * Dd;

  f32x4 hold = {0.f,0.f,0.f,0.f};              // fp32 h master, register-resident

  // prefetch x_0 fragments
  bf16x8 xa[16];
  if constexpr (XBF) {
    #pragma unroll
    for (int kk = 0; kk < 16; ++kk) xa[kk] = *(const bf16x8*)(xbrow + kk*32 + kg*8);
  } else {
    #pragma unroll
    for (int kk = 0; kk < 16; ++kk) {
      f32x4 v0 = *(const f32x4*)(xrow + kk*32 + kg*8);
      f32x4 v1 = *(const f32x4*)(xrow + kk*32 + kg*8 + 4);
      bf16x8 a;
      #pragma unroll
      for (int e = 0; e < 4; ++e) { ((unsigned short*)&a)[e] = f2bf(v0[e]); ((unsigned short*)&a)[e+4] = f2bf(v1[e]); }
      xa[kk] = a;
    }
  }

  for (int t = 0; t < Tt; ++t) {
    f32x4 az  = {0.f,0.f,0.f,0.f};
    f32x4 arr = {0.f,0.f,0.f,0.f};
    f32x4 axh = {0.f,0.f,0.f,0.f};
    f32x4 ahu = {0.f,0.f,0.f,0.f};

    // ---- x-part MFMAs (in the poll shadow; operands already in registers) ----
    #pragma unroll
    for (int kk = 0; kk < 16; ++kk) {
      bf16x8 bz = *(const bf16x8*)&lds[(0  + kk)*512 + lane*8];
      bf16x8 br = *(const bf16x8*)&lds[(48 + kk)*512 + lane*8];
      bf16x8 bx = *(const bf16x8*)&lds[(96 + kk)*512 + lane*8];
      az  = __builtin_amdgcn_mfma_f32_16x16x32_bf16(xa[kk], bz, az , 0,0,0);
      arr = __builtin_amdgcn_mfma_f32_16x16x32_bf16(xa[kk], br, arr, 0,0,0);
      axh = __builtin_amdgcn_mfma_f32_16x16x32_bf16(xa[kk], bx, axh, 0,0,0);
    }

    // issue x_{t+1} prefetch loads (land during h work / barrier)
    if (t + 1 < Tt) {
      if constexpr (XBF) {
        const unsigned short* xt = xbrow + (size_t)(t+1)*Dd;
        #pragma unroll
        for (int kk = 0; kk < 16; ++kk) xa[kk] = *(const bf16x8*)(xt + kk*32 + kg*8);
      } else {
        const float* xt = xrow + (size_t)(t+1)*Dd;
        #pragma unroll
        for (int kk = 0; kk < 16; ++kk) {
          f32x4 v0 = *(const f32x4*)(xt + kk*32 + kg*8);
          f32x4 v1 = *(const f32x4*)(xt + kk*32 + kg*8 + 4);
          bf16x8 a;
          #pragma unroll
          for (int e = 0; e < 4; ++e) { ((unsigned short*)&a)[e] = f2bf(v0[e]); ((unsigned short*)&a)[e+4] = f2bf(v1[e]); }
          xa[kk] = a;
        }
      }
    }

    if (t > 0) {
      // ---- wait for h[t]: relaxed device-scope RMW poll (no inv per iter) ----
      if (wave == 0) {
        for (;;) {
          unsigned v = __hip_atomic_fetch_add(&done[lane*8], 0u,
                           __ATOMIC_RELAXED, __HIP_MEMORY_SCOPE_AGENT);
          if (__all((int)(v >= (unsigned)t))) break;
          __builtin_amdgcn_s_sleep(1);
        }
        __builtin_amdgcn_fence(__ATOMIC_ACQUIRE, "agent");   // one buffer_inv/step
      }
      __syncthreads();

      // ---- h fragment loads (normal cached; L2 fresh after inv) ----
      const unsigned short* hrow = hb + (size_t)(t & 1)*(Bb*Hh) + (size_t)b*Hh;
      bf16x8 ha[32];
      #pragma unroll
      for (int kk = 0; kk < 32; ++kk)
        ha[kk] = *(const bf16x8*)(hrow + kk*32 + kg*8);

      // ---- h-part MFMAs ----
      #pragma unroll
      for (int kk = 0; kk < 32; ++kk) {
        bf16x8 bz = *(const bf16x8*)&lds[(16  + kk)*512 + lane*8];
        bf16x8 br = *(const bf16x8*)&lds[(64  + kk)*512 + lane*8];
        bf16x8 bu = *(const bf16x8*)&lds[(112 + kk)*512 + lane*8];
        az  = __builtin_amdgcn_mfma_f32_16x16x32_bf16(ha[kk], bz, az , 0,0,0);
        arr = __builtin_amdgcn_mfma_f32_16x16x32_bf16(ha[kk], br, arr, 0,0,0);
        ahu = __builtin_amdgcn_mfma_f32_16x16x32_bf16(ha[kk], bu, ahu, 0,0,0);
      }
    }

    // ---- gate epilogue: h_new = z*h + (1-z)*tanh(xh + (hU)*r) ----
    unsigned short hv[4];
    #pragma unroll
    for (int e = 0; e < 4; ++e) {
      float z  = 1.f / (1.f + __expf(-az[e]));
      float r  = 1.f / (1.f + __expf(-arr[e]));
      float u  = axh[e] + ahu[e] * r;
      float hh = 2.f / (1.f + __expf(-2.f * u)) - 1.f;    // tanh
      float hn = z*hold[e] + (1.f - z)*hh;
      hold[e]  = hn;
      hv[e]    = f2bf(hn);
    }

    if (t < Tt - 1) {
      // normal cached stores; release-exchange publishes them coherently
      unsigned short* hbw = hb + (size_t)((t+1) & 1)*(Bb*Hh);
      #pragma unroll
      for (int e = 0; e < 4; ++e) hbw[(size_t)(crow+e)*Hh + j] = hv[e];
      __syncthreads();                                   // all waves' stores in L2
      if (tid == 0) {
        __hip_atomic_exchange(&done[cblk*8], (unsigned)(t + 1),
                              __ATOMIC_RELEASE, __HIP_MEMORY_SCOPE_AGENT);
      }
    } else {
      #pragma unroll
      for (int e = 0; e < 4; ++e) hf[(size_t)(crow+e)*Hh + j] = hold[e];
    }
  }
}

// ---------------- classifier: p = h_last @ W_ph + b_p ----------------
__global__ void classifier(const float* __restrict__ h, const float* __restrict__ Wph,
                           const float* __restrict__ bp, float* __restrict__ out) {
  __shared__ float hsm[8 * Hh];                 // transposed: [k][r]
  const int cb = blockIdx.x, bbk = blockIdx.y;
  const int tid = threadIdx.x;
  const float* h0 = h + (size_t)bbk * 8 * Hh;
  for (int i = tid; i < 8 * Hh; i += 256) {
    int r = i >> 10, k = i & (Hh - 1);
    hsm[k*8 + r] = h0[i];
  }
  __syncthreads();
  int c = cb*256 + tid;
  bool act = c < Cc;
  float acc[8] = {0,0,0,0,0,0,0,0};
  for (int k = 0; k < Hh; ++k) {
    float w = act ? Wph[(size_t)k*Cc + c] : 0.f;
    f32x4 h0v = *(const f32x4*)&hsm[k*8];
    f32x4 h1v = *(const f32x4*)&hsm[k*8 + 4];
    acc[0] += h0v[0]*w; acc[1] += h0v[1]*w; acc[2] += h0v[2]*w; acc[3] += h0v[3]*w;
    acc[4] += h1v[0]*w; acc[5] += h1v[1]*w; acc[6] += h1v[2]*w; acc[7] += h1v[3]*w;
  }
  if (act) {
    float bias = bp[c];
    #pragma unroll
    for (int r = 0; r < 8; ++r) out[(size_t)(bbk*8 + r)*Cc + c] = acc[r] + bias;
  }
}

// ---------------- in-place log_softmax over rows of [256,1000] ----------------
__global__ void logsoftmax(float* __restrict__ out) {
  __shared__ float sm[4];
  float* row = out + (size_t)blockIdx.x * Cc;
  const int tid = threadIdx.x;
  float m = -3.4e38f;
  for (int i = tid; i < Cc; i += 256) m = fmaxf(m, row[i]);
  #pragma unroll
  for (int o = 32; o; o >>= 1) m = fmaxf(m, __shfl_down(m, o, 64));
  if ((tid & 63) == 0) sm[tid >> 6] = m;
  __syncthreads();
  m = fmaxf(fmaxf(sm[0], sm[1]), fmaxf(sm[2], sm[3]));
  __syncthreads();
  float s = 0.f;
  for (int i = tid; i < Cc; i += 256) s += __expf(row[i] - m);
  #pragma unroll
  for (int o = 32; o; o >>= 1) s += __shfl_down(s, o, 64);
  if ((tid & 63) == 0) sm[tid >> 6] = s;
  __syncthreads();
  s = sm[0] + sm[1] + sm[2] + sm[3];
  float lse = m + __logf(s);
  for (int i = tid; i < Cc; i += 256) row[i] -= lse;
}

extern "C" void kernel_launch(void* const* d_in, const int* in_sizes, int n_in,
                              void* d_out, int out_size, void* d_ws, size_t ws_size,
                              hipStream_t stream) {
  (void)in_sizes; (void)n_in; (void)out_size;
  const float* x   = (const float*)d_in[0];
  const float* Wz  = (const float*)d_in[1];
  const float* Wr  = (const float*)d_in[2];
  const float* W   = (const float*)d_in[3];
  const float* Uz  = (const float*)d_in[4];
  const float* Ur  = (const float*)d_in[5];
  const float* U   = (const float*)d_in[6];
  const float* Wph = (const float*)d_in[7];
  const float* bp  = (const float*)d_in[8];
  float* out = (float*)d_out;

  char* ws = (char*)d_ws;
  const size_t OFF_PACK = 0;                       // 9,437,184 B
  const size_t OFF_HF   = 9437184;                 // 1,048,576 B ([256,1024] fp32, final h)
  const size_t OFF_HB   = OFF_HF + 1048576;        // 1,048,576 B (2 x [256,1024] bf16)
  const size_t OFF_BAR  = OFF_HB + 1048576;        // 8,192 B flags (4 groups x 64 x 32B)
  const size_t OFF_XB   = OFF_BAR + 8192;          // 67,108,864 B ([B,T,D] bf16)
  unsigned short* packed = (unsigned short*)(ws + OFF_PACK);
  float*          hf     = (float*)(ws + OFF_HF);
  unsigned short* hb     = (unsigned short*)(ws + OFF_HB);
  unsigned*       bar    = (unsigned*)(ws + OFF_BAR);
  unsigned short* xbm    = (unsigned short*)(ws + OFF_XB);
  const bool xbf = ws_size >= OFF_XB + (size_t)67108864;

  // reset flags every call (runs inside the captured graph on each replay)
  hipMemsetAsync(bar, 0, 8192, stream);
  pack_weights<<<dim3(2304), dim3(256), 0, stream>>>(Wz, Wr, W, Uz, Ur, U, packed);
  if (xbf) cvt_x<<<dim3(2048), dim3(256), 0, stream>>>(x, xbm);

  void* args[] = { (void*)&x, (void*)&xbm, (void*)&packed, (void*)&hf, (void*)&hb, (void*)&bar };
  if (xbf) {
    hipLaunchCooperativeKernel(reinterpret_cast<void*>(&gru_scan<true>),
                               dim3(256), dim3(256), args, 0, stream);
  } else {
    hipLaunchCooperativeKernel(reinterpret_cast<void*>(&gru_scan<false>),
                               dim3(256), dim3(256), args, 0, stream);
  }

  classifier<<<dim3(4, 32), dim3(256), 0, stream>>>(hf, Wph, bp, out);
  logsoftmax<<<dim3(256), dim3(256), 0, stream>>>(out);
}

// Round 9
// 3060.052 us; speedup vs baseline: 3.6065x; 1.4758x over previous
//
#include <hip/hip_runtime.h>
#include <hip/hip_bf16.h>

// Problem dims
#define Bb 256
#define Tt 256
#define Dd 512
#define Hh 1024
#define Cc 1000

typedef short  bf16x8 __attribute__((ext_vector_type(8)));
typedef float  f32x4  __attribute__((ext_vector_type(4)));
typedef unsigned short u16x8 __attribute__((ext_vector_type(8)));

// 32-k chunks for MFMA 16x16x32. Per 16-col block:
//  z : 16 x-chunks [0,16) + 32 h-chunks [16,48)
//  r : 16 x-chunks [48,64) + 32 h-chunks [64,96)
//  xh: 16 x-chunks [96,112)
//  hU: 32 h-chunks [112,144)
#define NCI 144
// packed: [cblk(64)][ci(144)][lane(64)][8 elems] bf16 = 9,437,184 B

__device__ __forceinline__ unsigned short f2bf(float f) {
  unsigned u = __float_as_uint(f);
  u += 0x7FFFu + ((u >> 16) & 1u);       // RNE
  return (unsigned short)(u >> 16);
}

// ---------------- pack weights into MFMA-fragment order (bf16) ----------------
// B-fragment for 16x16x32: col = lane&15, k = (lane>>4)*8 + e
__global__ void pack_weights(const float* __restrict__ Wz, const float* __restrict__ Wr,
                             const float* __restrict__ W,  const float* __restrict__ Uz,
                             const float* __restrict__ Ur, const float* __restrict__ U,
                             unsigned short* __restrict__ packed) {
  int tid = blockIdx.x * 256 + threadIdx.x;           // one thread = one (c,ci,lane) -> 8 elems
  if (tid >= 64 * NCI * 64) return;
  int lane = tid & 63;
  int rest = tid >> 6;
  int ci   = rest % NCI;
  int c    = rest / NCI;                               // 0..63 col block
  int j    = (c << 4) + (lane & 15);                   // output column
  int kg   = lane >> 4;                                // 0..3
  const float* src; int kb;
  if      (ci < 16)  { src = Wz; kb = ci*32; }
  else if (ci < 48)  { src = Uz; kb = (ci-16)*32; }
  else if (ci < 64)  { src = Wr; kb = (ci-48)*32; }
  else if (ci < 96)  { src = Ur; kb = (ci-64)*32; }
  else if (ci < 112) { src = W;  kb = (ci-96)*32; }
  else               { src = U;  kb = (ci-112)*32; }
  int k0 = kb + kg*8;
  u16x8 o;
  #pragma unroll
  for (int e = 0; e < 8; ++e) o[e] = f2bf(src[(size_t)(k0+e)*Hh + j]);
  *(u16x8*)(packed + (size_t)tid*8) = o;
}

// ---------------- x fp32 -> bf16 (optional, if ws is big enough) ----------------
__global__ void cvt_x(const float* __restrict__ x, unsigned short* __restrict__ xb) {
  const int n4 = (Bb*Tt*Dd)/4;
  for (int i = blockIdx.x*256 + threadIdx.x; i < n4; i += gridDim.x*256) {
    f32x4 v = *(const f32x4*)(x + (size_t)i*4);
    unsigned short o[4];
    #pragma unroll
    for (int e = 0; e < 4; ++e) o[e] = f2bf(v[e]);
    *(unsigned long long*)(xb + (size_t)i*4) = *(unsigned long long*)o;
  }
}

// ---------------- one GRU timestep ----------------
// Launched 256x inside the captured graph. Kernel boundaries provide cross-XCD
// coherence via the command processor's per-dispatch L2 writeback/invalidate —
// the hardware-amortized form of the fences R2..R8 tried to hand-roll.
// grid = 256 WGs (4 row-blocks x 64 col-blocks), 256 threads (4 waves x 16 rows).
// h lives in ws: bf16 double-buffer (MFMA A-operand) + fp32 double-buffer
// (master for the z*h blend — keeps numerics identical to R6's register master).
template<bool T0, bool XBF>
__global__ void __launch_bounds__(256, 1)
gru_step(const float* __restrict__ x, const unsigned short* __restrict__ xb,
         const unsigned short* __restrict__ packed,
         const unsigned short* __restrict__ hbsrc, unsigned short* __restrict__ hbdst,
         const float* __restrict__ hfsrc, float* __restrict__ hfdst,
         int t) {
  __shared__ short lds[NCI * 512];                     // 147,456 B weight slice

  const int wg   = blockIdx.x;
  const int cblk = wg & 63;
  const int rblk = wg >> 6;
  const int tid  = threadIdx.x;
  const int lane = tid & 63;
  const int wave = tid >> 6;

  const int arow = lane & 15;                  // A row within wave's 16-row tile
  const int kg   = lane >> 4;                  // k-group 0..3 (k = kg*8 + e)
  const int b    = rblk*64 + wave*16 + arow;   // A-operand batch row
  const int crow = rblk*64 + wave*16 + kg*4;   // C/D row base (+e)
  const int j    = (cblk << 4) + arow;         // C/D column

  // ---- issue h A-fragment loads first (longest latency; fresh: kernel boundary) ----
  bf16x8 ha[32];
  float  hold[4];
  if constexpr (!T0) {
    const unsigned short* hrow = hbsrc + (size_t)b * Hh;
    #pragma unroll
    for (int kk = 0; kk < 32; ++kk) ha[kk] = *(const bf16x8*)(hrow + kk*32 + kg*8);
    #pragma unroll
    for (int e = 0; e < 4; ++e) hold[e] = hfsrc[(size_t)(crow+e)*Hh + j];
  } else {
    #pragma unroll
    for (int e = 0; e < 4; ++e) hold[e] = 0.f;
  }

  // ---- stage this col-block's weight slice into LDS (36 x 16B per thread) ----
  {
    const u16x8* s8 = (const u16x8*)(packed + (size_t)cblk * (NCI * 512));
    u16x8* d8 = (u16x8*)lds;
    #pragma unroll
    for (int i = 0; i < 36; ++i) d8[tid + i*256] = s8[tid + i*256];
  }

  // ---- x A-fragments ----
  bf16x8 xa[16];
  if constexpr (XBF) {
    const unsigned short* xt = xb + ((size_t)b * Tt + t) * Dd;
    #pragma unroll
    for (int kk = 0; kk < 16; ++kk) xa[kk] = *(const bf16x8*)(xt + kk*32 + kg*8);
  } else {
    const float* xt = x + ((size_t)b * Tt + t) * Dd;
    #pragma unroll
    for (int kk = 0; kk < 16; ++kk) {
      f32x4 v0 = *(const f32x4*)(xt + kk*32 + kg*8);
      f32x4 v1 = *(const f32x4*)(xt + kk*32 + kg*8 + 4);
      bf16x8 a;
      #pragma unroll
      for (int e = 0; e < 4; ++e) { ((unsigned short*)&a)[e] = f2bf(v0[e]); ((unsigned short*)&a)[e+4] = f2bf(v1[e]); }
      xa[kk] = a;
    }
  }

  __syncthreads();                                     // staging + loads complete

  f32x4 az  = {0.f,0.f,0.f,0.f};
  f32x4 arr = {0.f,0.f,0.f,0.f};
  f32x4 axh = {0.f,0.f,0.f,0.f};
  f32x4 ahu = {0.f,0.f,0.f,0.f};

  // x-part
  #pragma unroll
  for (int kk = 0; kk < 16; ++kk) {
    bf16x8 bz = *(const bf16x8*)&lds[(0  + kk)*512 + lane*8];
    bf16x8 br = *(const bf16x8*)&lds[(48 + kk)*512 + lane*8];
    bf16x8 bx = *(const bf16x8*)&lds[(96 + kk)*512 + lane*8];
    az  = __builtin_amdgcn_mfma_f32_16x16x32_bf16(xa[kk], bz, az , 0,0,0);
    arr = __builtin_amdgcn_mfma_f32_16x16x32_bf16(xa[kk], br, arr, 0,0,0);
    axh = __builtin_amdgcn_mfma_f32_16x16x32_bf16(xa[kk], bx, axh, 0,0,0);
  }
  // h-part
  if constexpr (!T0) {
    #pragma unroll
    for (int kk = 0; kk < 32; ++kk) {
      bf16x8 bz = *(const bf16x8*)&lds[(16  + kk)*512 + lane*8];
      bf16x8 br = *(const bf16x8*)&lds[(64  + kk)*512 + lane*8];
      bf16x8 bu = *(const bf16x8*)&lds[(112 + kk)*512 + lane*8];
      az  = __builtin_amdgcn_mfma_f32_16x16x32_bf16(ha[kk], bz, az , 0,0,0);
      arr = __builtin_amdgcn_mfma_f32_16x16x32_bf16(ha[kk], br, arr, 0,0,0);
      ahu = __builtin_amdgcn_mfma_f32_16x16x32_bf16(ha[kk], bu, ahu, 0,0,0);
    }
  }

  // ---- gate epilogue: h_new = z*h + (1-z)*tanh(xh + (hU)*r) ----
  #pragma unroll
  for (int e = 0; e < 4; ++e) {
    float z  = 1.f / (1.f + __expf(-az[e]));
    float r  = 1.f / (1.f + __expf(-arr[e]));
    float u  = axh[e] + ahu[e] * r;
    float hh = 2.f / (1.f + __expf(-2.f * u)) - 1.f;    // tanh
    float hn = z*hold[e] + (1.f - z)*hh;
    hfdst[(size_t)(crow+e)*Hh + j] = hn;                // fp32 master
    hbdst[(size_t)(crow+e)*Hh + j] = f2bf(hn);          // bf16 operand copy
  }
}

// ---------------- classifier: p = h_last @ W_ph + b_p ----------------
__global__ void classifier(const float* __restrict__ h, const float* __restrict__ Wph,
                           const float* __restrict__ bp, float* __restrict__ out) {
  __shared__ float hsm[8 * Hh];                 // transposed: [k][r]
  const int cb = blockIdx.x, bbk = blockIdx.y;
  const int tid = threadIdx.x;
  const float* h0 = h + (size_t)bbk * 8 * Hh;
  for (int i = tid; i < 8 * Hh; i += 256) {
    int r = i >> 10, k = i & (Hh - 1);
    hsm[k*8 + r] = h0[i];
  }
  __syncthreads();
  int c = cb*256 + tid;
  bool act = c < Cc;
  float acc[8] = {0,0,0,0,0,0,0,0};
  for (int k = 0; k < Hh; ++k) {
    float w = act ? Wph[(size_t)k*Cc + c] : 0.f;
    f32x4 h0v = *(const f32x4*)&hsm[k*8];
    f32x4 h1v = *(const f32x4*)&hsm[k*8 + 4];
    acc[0] += h0v[0]*w; acc[1] += h0v[1]*w; acc[2] += h0v[2]*w; acc[3] += h0v[3]*w;
    acc[4] += h1v[0]*w; acc[5] += h1v[1]*w; acc[6] += h1v[2]*w; acc[7] += h1v[3]*w;
  }
  if (act) {
    float bias = bp[c];
    #pragma unroll
    for (int r = 0; r < 8; ++r) out[(size_t)(bbk*8 + r)*Cc + c] = acc[r] + bias;
  }
}

// ---------------- in-place log_softmax over rows of [256,1000] ----------------
__global__ void logsoftmax(float* __restrict__ out) {
  __shared__ float sm[4];
  float* row = out + (size_t)blockIdx.x * Cc;
  const int tid = threadIdx.x;
  float m = -3.4e38f;
  for (int i = tid; i < Cc; i += 256) m = fmaxf(m, row[i]);
  #pragma unroll
  for (int o = 32; o; o >>= 1) m = fmaxf(m, __shfl_down(m, o, 64));
  if ((tid & 63) == 0) sm[tid >> 6] = m;
  __syncthreads();
  m = fmaxf(fmaxf(sm[0], sm[1]), fmaxf(sm[2], sm[3]));
  __syncthreads();
  float s = 0.f;
  for (int i = tid; i < Cc; i += 256) s += __expf(row[i] - m);
  #pragma unroll
  for (int o = 32; o; o >>= 1) s += __shfl_down(s, o, 64);
  if ((tid & 63) == 0) sm[tid >> 6] = s;
  __syncthreads();
  s = sm[0] + sm[1] + sm[2] + sm[3];
  float lse = m + __logf(s);
  for (int i = tid; i < Cc; i += 256) row[i] -= lse;
}

extern "C" void kernel_launch(void* const* d_in, const int* in_sizes, int n_in,
                              void* d_out, int out_size, void* d_ws, size_t ws_size,
                              hipStream_t stream) {
  (void)in_sizes; (void)n_in; (void)out_size;
  const float* x   = (const float*)d_in[0];
  const float* Wz  = (const float*)d_in[1];
  const float* Wr  = (const float*)d_in[2];
  const float* W   = (const float*)d_in[3];
  const float* Uz  = (const float*)d_in[4];
  const float* Ur  = (const float*)d_in[5];
  const float* U   = (const float*)d_in[6];
  const float* Wph = (const float*)d_in[7];
  const float* bp  = (const float*)d_in[8];
  float* out = (float*)d_out;

  char* ws = (char*)d_ws;
  const size_t OFF_PACK = 0;                       // 9,437,184 B
  const size_t OFF_HB   = 9437184;                 // 1,048,576 B (2 x [256,1024] bf16)
  const size_t OFF_HF   = OFF_HB + 1048576;        // 2,097,152 B (2 x [256,1024] fp32)
  const size_t OFF_XB   = OFF_HF + 2097152;        // 67,108,864 B ([B,T,D] bf16)
  unsigned short* packed = (unsigned short*)(ws + OFF_PACK);
  unsigned short* hb     = (unsigned short*)(ws + OFF_HB);
  float*          hfm    = (float*)(ws + OFF_HF);
  unsigned short* xbm    = (unsigned short*)(ws + OFF_XB);
  const bool xbf = ws_size >= OFF_XB + (size_t)67108864;

  pack_weights<<<dim3(2304), dim3(256), 0, stream>>>(Wz, Wr, W, Uz, Ur, U, packed);
  if (xbf) cvt_x<<<dim3(2048), dim3(256), 0, stream>>>(x, xbm);

  const int HB = Bb * Hh;
  for (int t = 0; t < Tt; ++t) {
    const int rd = t & 1, wr = rd ^ 1;
    const unsigned short* hbs = hb  + (size_t)rd * HB;
    unsigned short*       hbd = hb  + (size_t)wr * HB;
    const float*          hfs = hfm + (size_t)rd * HB;
    float*                hfd = hfm + (size_t)wr * HB;
    if (t == 0) {
      if (xbf) gru_step<true,  true ><<<dim3(256), dim3(256), 0, stream>>>(x, xbm, packed, hbs, hbd, hfs, hfd, t);
      else     gru_step<true,  false><<<dim3(256), dim3(256), 0, stream>>>(x, xbm, packed, hbs, hbd, hfs, hfd, t);
    } else {
      if (xbf) gru_step<false, true ><<<dim3(256), dim3(256), 0, stream>>>(x, xbm, packed, hbs, hbd, hfs, hfd, t);
      else     gru_step<false, false><<<dim3(256), dim3(256), 0, stream>>>(x, xbm, packed, hbs, hbd, hfs, hfd, t);
    }
  }

  // after t=255, h_last (fp32) is in buffer (256 & 1) == 0
  classifier<<<dim3(4, 32), dim3(256), 0, stream>>>(hfm, Wph, bp, out);
  logsoftmax<<<dim3(256), dim3(256), 0, stream>>>(out);
}